// Round 1
// baseline (177.701 us; speedup 1.0000x reference)
//
#include <hip/hip_runtime.h>

// Sinkhorn (log-domain, dustbin-augmented) fully fused in one kernel.
//
// Math (base-2 domain; L = log2(e)):
//   s' = s*L, u' = u*L, v' = v*L, a' = alpha*L
//   L*norm = -log2(m+n) = -9 exactly (m=n=256); L*log_mu[m] = log2(n)+L*norm = -1
//   u'_i  = -9 - log2( sum_j 2^{s'_ij} * 2^{v'_j} + 2^{a'+v'_256} ),  i<256
//   u'_256= -1 - a' - log2( sum_{j<=256} 2^{v'_j} )
//   v'_j  = -9 - log2( sum_i 2^{s'_ij} * 2^{u'_i} + 2^{a'+u'_256} ),  j<256
//   v'_256= -1 - a' - log2( sum_{i<=256} 2^{u'_i} )
//   Z     = (s' + u' + v' + 9) * ln2   (couplings dustbin entries use a' for s')
//
// Each block owns one batch; thread (a,b) holds an 8x8 tile of 2^{s'} in VGPRs.

#define PS 264  // padded LDS row stride (floats)

__device__ __forceinline__ float fexp2(float x) { return __builtin_amdgcn_exp2f(x); }
__device__ __forceinline__ float flog2(float x) { return __builtin_amdgcn_logf(x); }

constexpr float L2E = 1.4426950408889634f;
constexpr float LN2 = 0.6931471805599453f;

__global__ __launch_bounds__(1024) void sinkhorn_kernel(
    const float* __restrict__ scores,
    const float* __restrict__ alpha_p,
    const int*   __restrict__ iters_p,
    float* __restrict__ out)
{
    const int bat = blockIdx.x;
    const int t   = threadIdx.x;
    const int a   = t >> 5;     // row-group 0..31 (rows 8a..8a+7)
    const int bb  = t & 31;     // col-group 0..31 (cols 8bb..8bb+7)

    const float alpha2 = alpha_p[0] * L2E;
    const int iters = iters_p[0];

    __shared__ __align__(16) float sbuf[32 * PS];  // col partials (rows 0..15) / output staging (rows 0..31)
    __shared__ __align__(16) float vbuf[264];      // v' (257 used)

    // ---- load scores tile once; keep as es = 2^(s * log2e) in registers ----
    float es[8][8];
    const float* sp = scores + ((size_t)bat << 16) + (size_t)(a << 11) + (bb << 3);
    #pragma unroll
    for (int r = 0; r < 8; ++r) {
        const float4* p4 = reinterpret_cast<const float4*>(sp + (r << 8));
        float4 x0 = p4[0];
        float4 x1 = p4[1];
        es[r][0] = fexp2(x0.x * L2E);
        es[r][1] = fexp2(x0.y * L2E);
        es[r][2] = fexp2(x0.z * L2E);
        es[r][3] = fexp2(x0.w * L2E);
        es[r][4] = fexp2(x1.x * L2E);
        es[r][5] = fexp2(x1.y * L2E);
        es[r][6] = fexp2(x1.z * L2E);
        es[r][7] = fexp2(x1.w * L2E);
    }

    if (t < 257) vbuf[t] = 0.0f;   // v0 = 0
    float ul[8];
    #pragma unroll
    for (int r = 0; r < 8; ++r) ul[r] = 0.0f;
    float udust = 0.0f;
    float vdust = 0.0f;
    __syncthreads();

    for (int it = 0; it < iters; ++it) {
        // ================= row phase: u from v =================
        vdust = vbuf[256];
        const float4 v0 = *reinterpret_cast<const float4*>(&vbuf[bb << 3]);
        const float4 v1 = *reinterpret_cast<const float4*>(&vbuf[(bb << 3) + 4]);
        float evl[8];
        evl[0] = fexp2(v0.x); evl[1] = fexp2(v0.y); evl[2] = fexp2(v0.z); evl[3] = fexp2(v0.w);
        evl[4] = fexp2(v1.x); evl[5] = fexp2(v1.y); evl[6] = fexp2(v1.z); evl[7] = fexp2(v1.w);

        // sum_j 2^{v'_j} (j<256) for the dustbin u-row; identical across a-groups
        float vs = ((evl[0]+evl[1])+(evl[2]+evl[3]))+((evl[4]+evl[5])+(evl[6]+evl[7]));
        #pragma unroll
        for (int o = 1; o < 32; o <<= 1) vs += __shfl_xor(vs, o, 64);
        udust = -1.0f - alpha2 - flog2(vs + fexp2(vdust));

        const float tdv = fexp2(alpha2 + vdust);   // dustbin-column term, same for every row
        #pragma unroll
        for (int r = 0; r < 8; ++r) {
            float p = es[r][0] * evl[0];
            #pragma unroll
            for (int c = 1; c < 8; ++c) p = fmaf(es[r][c], evl[c], p);
            #pragma unroll
            for (int o = 1; o < 32; o <<= 1) p += __shfl_xor(p, o, 64);  // allreduce over 32 col-groups
            ul[r] = -9.0f - flog2(p + tdv);
        }

        // ================= col phase: v from (new) u =================
        float eul[8];
        #pragma unroll
        for (int r = 0; r < 8; ++r) eul[r] = fexp2(ul[r]);
        float us = ((eul[0]+eul[1])+(eul[2]+eul[3]))+((eul[4]+eul[5])+(eul[6]+eul[7]));
        float pc[8];
        #pragma unroll
        for (int c = 0; c < 8; ++c) {
            float q = es[0][c] * eul[0];
            #pragma unroll
            for (int r = 1; r < 8; ++r) q = fmaf(es[r][c], eul[r], q);
            pc[c] = q;
        }
        // fold lane pairs (a=2w with a=2w+1) so only 16 partial rows hit LDS
        #pragma unroll
        for (int c = 0; c < 8; ++c) pc[c] += __shfl_xor(pc[c], 32, 64);
        us += __shfl_xor(us, 32, 64);

        const float tdu = fexp2(alpha2 + udust);
        const float edu = fexp2(udust);

        __syncthreads();  // previous readers of sbuf/vbuf are done
        if ((t & 32) == 0) {
            const int w = t >> 6;  // wave id 0..15
            float4* dst = reinterpret_cast<float4*>(&sbuf[w * PS + (bb << 3)]);
            dst[0] = make_float4(pc[0], pc[1], pc[2], pc[3]);
            dst[1] = make_float4(pc[4], pc[5], pc[6], pc[7]);
            if (bb == 0) sbuf[w * PS + 256] = us;   // partial sum_i 2^{u'_i}
        }
        __syncthreads();
        if (t < 257) {
            float q0 = 0.f, q1 = 0.f, q2 = 0.f, q3 = 0.f;
            #pragma unroll
            for (int w2 = 0; w2 < 16; w2 += 4) {
                q0 += sbuf[(w2 + 0) * PS + t];
                q1 += sbuf[(w2 + 1) * PS + t];
                q2 += sbuf[(w2 + 2) * PS + t];
                q3 += sbuf[(w2 + 3) * PS + t];
            }
            const float q = (q0 + q1) + (q2 + q3);
            vbuf[t] = (t < 256) ? (-9.0f - flog2(q + tdu))
                                : (-1.0f - alpha2 - flog2(q + edu));
        }
        __syncthreads();
    }

    // ================= output: Z = (s' + u' + v' + 9) * ln2 =================
    vdust = vbuf[256];
    const float4 v0 = *reinterpret_cast<const float4*>(&vbuf[bb << 3]);
    const float4 v1 = *reinterpret_cast<const float4*>(&vbuf[(bb << 3) + 4]);
    float vl[8] = {v0.x, v0.y, v0.z, v0.w, v1.x, v1.y, v1.z, v1.w};

    const size_t ob = (size_t)bat * 66049;  // 257*257
    #pragma unroll
    for (int r = 0; r < 8; ++r) {
        __syncthreads();  // previous round's global writes consumed sbuf
        {
            const float su = ul[r] + 9.0f;
            float z[8];
            #pragma unroll
            for (int c = 0; c < 8; ++c)
                z[c] = (flog2(es[r][c]) + su + vl[c]) * LN2;  // s' = log2(es)
            float4* dst = reinterpret_cast<float4*>(&sbuf[a * PS + (bb << 3)]);
            dst[0] = make_float4(z[0], z[1], z[2], z[3]);
            dst[1] = make_float4(z[4], z[5], z[6], z[7]);
            if (bb == 0) sbuf[a * PS + 256] = (alpha2 + ul[r] + vdust + 9.0f) * LN2;  // dustbin col
        }
        __syncthreads();
        // cooperative coalesced store of 32 rows x 257 floats
        const size_t rbase = ob + (size_t)((a << 3) + r) * 257;
        for (int j = bb; j < 257; j += 32) out[rbase + j] = sbuf[a * PS + j];
    }
    // dustbin row (i = 256), incl. corner (vbuf[256] == vdust)
    if (t < 257) {
        out[ob + 65792 + t] = (alpha2 + udust + vbuf[t] + 9.0f) * LN2;
    }
}

extern "C" void kernel_launch(void* const* d_in, const int* in_sizes, int n_in,
                              void* d_out, int out_size, void* d_ws, size_t ws_size,
                              hipStream_t stream)
{
    const float* scores = (const float*)d_in[0];
    const float* alpha  = (const float*)d_in[1];
    const int*   iters  = (const int*)d_in[2];
    float* out = (float*)d_out;
    const int B = in_sizes[0] >> 16;  // / (256*256)
    hipLaunchKernelGGL(sinkhorn_kernel, dim3(B), dim3(1024), 0, stream,
                       scores, alpha, iters, out);
}